// Round 9
// baseline (92.684 us; speedup 1.0000x reference)
//
#include <hip/hip_runtime.h>

// ConvAttention collapse:
//   softmax_j(Aq[i]+Ak[j]+ba) == softmax_j(Ak_linear[j])   (i-terms & biases cancel)
//   out[i] = Wv * (sum_j sm[j] * x[j]) + bv                (identical for all i)
// Pipeline: k_prep -> k_z (per-px 25x128 GEMV, b128 weight reads)
//           -> k_ak (tap shift-sum) -> k_xbar (in-thread softmax + weighted avg)
//           -> k_mat (128x128 matvec + 16x broadcast store, XCD-swizzled)

#define HW    9216      // 96*96
#define HDIM  96
#define WDIM  96
#define CDIM  128
#define WP    28        // padded taps per row (16B-aligned rows)

__device__ __forceinline__ void fma4(float4& a, const float4& x, const float4& s) {
    a.x += x.x * s.x; a.y += x.y * s.y; a.z += x.z * s.z; a.w += x.w * s.w;
}
__device__ __forceinline__ void axpy4(float4& o, float w, const float4& v) {
    o.x += w * v.x; o.y += w * v.y; o.z += w * v.z; o.w += w * v.w;
}

// ---------------- K0: prep — weffp padded (blocks 0..13) + Wv^T (14..77) --
// weffp[c'][tap] = sum_c Wk[c][c'] * Wa[(128+c)][tap], rows padded to 28.
__global__ void k_prep(const float* __restrict__ Wk, const float* __restrict__ Wa,
                       const float* __restrict__ Wv,
                       float* __restrict__ weffp, float* __restrict__ wvt) {
    const int b = blockIdx.x;
    if (b < 14) {
        int idx = b * 256 + threadIdx.x;
        if (idx < 128 * WP) {
            int cp = idx / WP, tap = idx % WP;
            float s = 0.f;
            if (tap < 25)
                for (int c = 0; c < 128; ++c)
                    s += Wk[c * 128 + cp] * Wa[(128 + c) * 25 + tap];
            weffp[idx] = s;
        }
    } else {
        int idx = (b - 14) * 256 + threadIdx.x;        // 0..16383
        wvt[(idx & 127) * 128 + (idx >> 7)] = Wv[idx]; // wvt[c'][c] = Wv[c][c']
    }
}

// ---------------- K1: z[j][t][hw] = sum_c weff[c][t] * x[j][c][hw] ---------
// 7 float4 accumulators (28 taps, 3 dead); weights via ds_read_b128.
__global__ __launch_bounds__(256) void k_z(const float* __restrict__ x,
                                           const float* __restrict__ weffp,
                                           float* __restrict__ z) {
    __shared__ float wsm[128 * WP];
    const int tid = threadIdx.x;
    for (int i = tid * 4; i < 128 * WP; i += 1024)
        *(float4*)(wsm + i) = *(const float4*)(weffp + i);
    __syncthreads();

    const int j  = blockIdx.y;
    const int hw = blockIdx.x * 256 + tid;
    const float* xb = x + (size_t)j * CDIM * HW + hw;

    float4 a0 = make_float4(0.f, 0.f, 0.f, 0.f);
    float4 a1 = a0, a2 = a0, a3 = a0, a4 = a0, a5 = a0, a6 = a0;

    #pragma unroll 4
    for (int c = 0; c < 128; ++c) {
        float xv = xb[(size_t)c * HW];
        const float4* wr = (const float4*)(wsm + c * WP);
        float4 w;
        w = wr[0]; a0.x = fmaf(w.x, xv, a0.x); a0.y = fmaf(w.y, xv, a0.y);
                   a0.z = fmaf(w.z, xv, a0.z); a0.w = fmaf(w.w, xv, a0.w);
        w = wr[1]; a1.x = fmaf(w.x, xv, a1.x); a1.y = fmaf(w.y, xv, a1.y);
                   a1.z = fmaf(w.z, xv, a1.z); a1.w = fmaf(w.w, xv, a1.w);
        w = wr[2]; a2.x = fmaf(w.x, xv, a2.x); a2.y = fmaf(w.y, xv, a2.y);
                   a2.z = fmaf(w.z, xv, a2.z); a2.w = fmaf(w.w, xv, a2.w);
        w = wr[3]; a3.x = fmaf(w.x, xv, a3.x); a3.y = fmaf(w.y, xv, a3.y);
                   a3.z = fmaf(w.z, xv, a3.z); a3.w = fmaf(w.w, xv, a3.w);
        w = wr[4]; a4.x = fmaf(w.x, xv, a4.x); a4.y = fmaf(w.y, xv, a4.y);
                   a4.z = fmaf(w.z, xv, a4.z); a4.w = fmaf(w.w, xv, a4.w);
        w = wr[5]; a5.x = fmaf(w.x, xv, a5.x); a5.y = fmaf(w.y, xv, a5.y);
                   a5.z = fmaf(w.z, xv, a5.z); a5.w = fmaf(w.w, xv, a5.w);
        w = wr[6]; a6.x = fmaf(w.x, xv, a6.x);
    }
    float* zb = z + (size_t)j * 25 * HW + hw;
    zb[ 0*(size_t)HW] = a0.x; zb[ 1*(size_t)HW] = a0.y; zb[ 2*(size_t)HW] = a0.z; zb[ 3*(size_t)HW] = a0.w;
    zb[ 4*(size_t)HW] = a1.x; zb[ 5*(size_t)HW] = a1.y; zb[ 6*(size_t)HW] = a1.z; zb[ 7*(size_t)HW] = a1.w;
    zb[ 8*(size_t)HW] = a2.x; zb[ 9*(size_t)HW] = a2.y; zb[10*(size_t)HW] = a2.z; zb[11*(size_t)HW] = a2.w;
    zb[12*(size_t)HW] = a3.x; zb[13*(size_t)HW] = a3.y; zb[14*(size_t)HW] = a3.z; zb[15*(size_t)HW] = a3.w;
    zb[16*(size_t)HW] = a4.x; zb[17*(size_t)HW] = a4.y; zb[18*(size_t)HW] = a4.z; zb[19*(size_t)HW] = a4.w;
    zb[20*(size_t)HW] = a5.x; zb[21*(size_t)HW] = a5.y; zb[22*(size_t)HW] = a5.z; zb[23*(size_t)HW] = a5.w;
    zb[24*(size_t)HW] = a6.x;
}

// ---------------- K2: ak[j][px] = sum_t z[j][t][px + off(t)] (bounded) -----
__global__ __launch_bounds__(256) void k_ak(const float* __restrict__ z,
                                            float* __restrict__ ak) {
    const int j  = blockIdx.y;
    const int px = blockIdx.x * 256 + threadIdx.x;
    const int h = px / WDIM, w = px % WDIM;
    const float* zb = z + (size_t)j * 25 * HW + px;
    float s = 0.f;
    #pragma unroll
    for (int kh = 0; kh < 5; ++kh) {
        const bool rok = (unsigned)(h + kh - 2) < (unsigned)HDIM;
        #pragma unroll
        for (int kw = 0; kw < 5; ++kw) {
            const bool ok = rok && ((unsigned)(w + kw - 2) < (unsigned)WDIM);
            const int t = kh * 5 + kw;
            s += ok ? zb[t * HW + (kh - 2) * WDIM + (kw - 2)] : 0.f;
        }
    }
    ak[(size_t)j * HW + px] = s;
}

// ---------------- fallback conv path (small-ws; proven round 5) ------------
__global__ __launch_bounds__(192) void k_conv(const float* __restrict__ x,
                                              const float* __restrict__ weffp,
                                              float* __restrict__ part) {
    const int j  = blockIdx.x;
    const int rt = blockIdx.y;
    const int g  = blockIdx.z;
    const int c0 = g * 16;
    __shared__ float tile[36 * 104];
    __shared__ float wsm[16 * WP];
    const int tid = threadIdx.x;
    for (int i = tid; i < 16 * WP; i += 192) wsm[i] = weffp[c0 * WP + i];
    const int cq = tid % 24;
    const int rg = tid / 24;
    const int r0 = rg * 4;
    const int rowbase = rt * 32;

    float4 acc[4];
    acc[0] = acc[1] = acc[2] = acc[3] = make_float4(0.f, 0.f, 0.f, 0.f);

    for (int ch = 0; ch < 16; ++ch) {
        const float* xc = x + (size_t)(j * CDIM + c0 + ch) * HW;
        __syncthreads();
        for (int idx = tid; idx < 36 * 26; idx += 192) {
            int r = idx / 26, q = idx % 26;
            int gr = rowbase - 2 + r;
            int gc = q * 4 - 4;
            float4 v = make_float4(0.f, 0.f, 0.f, 0.f);
            if (gr >= 0 && gr < HDIM && gc >= 0 && gc < WDIM)
                v = *(const float4*)(xc + gr * WDIM + gc);
            *(float4*)(tile + r * 104 + q * 4) = v;
        }
        __syncthreads();
        const float* wc = wsm + ch * WP;
        for (int rr = 0; rr < 8; ++rr) {
            const float* trow = tile + (r0 + rr) * 104 + cq * 4;
            float4 a  = *(const float4*)(trow);
            float4 b  = *(const float4*)(trow + 4);
            float4 c4 = *(const float4*)(trow + 8);
            float win[12] = {a.x, a.y, a.z, a.w, b.x, b.y, b.z, b.w,
                             c4.x, c4.y, c4.z, c4.w};
            #pragma unroll
            for (int orow = 0; orow < 4; ++orow) {
                int kh = rr - orow;
                if (kh < 0 || kh > 4) continue;
                #pragma unroll
                for (int kw = 0; kw < 5; ++kw) {
                    float w = wc[kh * 5 + kw];
                    acc[orow].x += w * win[kw + 2];
                    acc[orow].y += w * win[kw + 3];
                    acc[orow].z += w * win[kw + 4];
                    acc[orow].w += w * win[kw + 5];
                }
            }
        }
    }
    float* pr = part + (size_t)(g * 16 + j) * HW;
    #pragma unroll
    for (int orow = 0; orow < 4; ++orow) {
        int row = rowbase + r0 + orow;
        *(float4*)(pr + row * WDIM + cq * 4) = acc[orow];
    }
}

__global__ void k_combine(const float* __restrict__ part, float* __restrict__ ak) {
    const int j  = blockIdx.y;
    const int px = blockIdx.x * 256 + threadIdx.x;
    float s = 0.f;
    #pragma unroll
    for (int g = 0; g < 8; ++g) s += part[(size_t)(g * 16 + j) * HW + px];
    ak[(size_t)j * HW + px] = s;
}

// ---------------- K3: xbar[cp][px] = sum_j softmax_j(ak)[px] * x[j][cp][px] -
__global__ __launch_bounds__(256) void k_xbar(const float* __restrict__ x,
                                              const float* __restrict__ ak,
                                              float* __restrict__ xbar) {
    const int b  = blockIdx.x;
    const int cp = b / 9;
    const int px = (b % 9) * 1024 + threadIdx.x * 4;

    float4 av[16];
    #pragma unroll
    for (int j = 0; j < 16; ++j)
        av[j] = *(const float4*)(ak + (size_t)j * HW + px);

    float4 m = av[0];
    #pragma unroll
    for (int j = 1; j < 16; ++j) {
        m.x = fmaxf(m.x, av[j].x); m.y = fmaxf(m.y, av[j].y);
        m.z = fmaxf(m.z, av[j].z); m.w = fmaxf(m.w, av[j].w);
    }
    float4 tot = make_float4(0.f, 0.f, 0.f, 0.f);
    #pragma unroll
    for (int j = 0; j < 16; ++j) {
        av[j].x = __expf(av[j].x - m.x); av[j].y = __expf(av[j].y - m.y);
        av[j].z = __expf(av[j].z - m.z); av[j].w = __expf(av[j].w - m.w);
        tot.x += av[j].x; tot.y += av[j].y; tot.z += av[j].z; tot.w += av[j].w;
    }
    float4 inv = make_float4(1.f / tot.x, 1.f / tot.y, 1.f / tot.z, 1.f / tot.w);

    float4 acc = make_float4(0.f, 0.f, 0.f, 0.f);
    #pragma unroll
    for (int j = 0; j < 16; ++j) {
        float4 xv = *(const float4*)(x + (size_t)(j * CDIM + cp) * HW + px);
        fma4(acc, xv, av[j]);
    }
    acc.x *= inv.x; acc.y *= inv.y; acc.z *= inv.z; acc.w *= inv.w;
    *(float4*)(xbar + (size_t)cp * HW + px) = acc;
}

// ---------------- K4: out[i][c][px] = Wv*xbar + bv, 16x broadcast ----------
__global__ __launch_bounds__(256) void k_mat(const float* __restrict__ xbar,
                                             const float* __restrict__ wvt,
                                             const float* __restrict__ bv,
                                             float* __restrict__ out) {
    __shared__ float lx[128 * 16];
    const int b    = blockIdx.x;
    const int tile = (b & 7) * 72 + (b >> 3);   // 576 = 8 * 72
    const int px0  = tile * 16;
    const int tid  = threadIdx.x;

    #pragma unroll
    for (int i = 0; i < 2; ++i) {
        int lin = tid + i * 256;                // 0..511
        int cp = lin >> 2, q = lin & 3;
        *(float4*)(lx + cp * 16 + q * 4) =
            *(const float4*)(xbar + (size_t)cp * HW + px0 + q * 4);
    }
    __syncthreads();

    const int q  = tid & 3;
    const int c0 = (tid >> 2) * 2;
    float4 o0 = make_float4(0.f, 0.f, 0.f, 0.f), o1 = o0;
    #pragma unroll 4
    for (int cp = 0; cp < 128; ++cp) {
        float4 xv = *(const float4*)(lx + cp * 16 + q * 4);
        float2 wv = *(const float2*)(wvt + cp * 128 + c0);
        axpy4(o0, wv.x, xv);
        axpy4(o1, wv.y, xv);
    }
    float b0 = bv[c0], b1 = bv[c0 + 1];
    o0.x += b0; o0.y += b0; o0.z += b0; o0.w += b0;
    o1.x += b1; o1.y += b1; o1.z += b1; o1.w += b1;

    for (int i = 0; i < 16; ++i) {
        float* ob = out + (size_t)(i * CDIM + c0) * HW + px0 + q * 4;
        *(float4*)(ob)      = o0;
        *(float4*)(ob + HW) = o1;
    }
}

extern "C" void kernel_launch(void* const* d_in, const int* in_sizes, int n_in,
                              void* d_out, int out_size, void* d_ws, size_t ws_size,
                              hipStream_t stream) {
    const float* x  = (const float*)d_in[0];
    const float* Wk = (const float*)d_in[3];
    const float* Wv = (const float*)d_in[5];
    const float* bv = (const float*)d_in[6];
    const float* Wa = (const float*)d_in[7];
    float* out = (float*)d_out;

    char* ws = (char*)d_ws;
    float* weffp = (float*)(ws);            // 128*28*4 = 14,336 B
    float* wvt   = (float*)(ws + 16384);    // 64 KB, ends 81920

    k_prep<<<78, 256, 0, stream>>>(Wk, Wa, Wv, weffp, wvt);

    const size_t Z_BYTES  = (size_t)16 * 25 * HW * 4;   // 14.75 MB
    const size_t AK_BYTES = (size_t)16 * HW * 4;        // 590 KB
    const size_t NEED_BIG = 81920 + Z_BYTES + AK_BYTES; // 15.4 MB (proven fits)

    if (ws_size >= NEED_BIG) {
        float* z    = (float*)(ws + 81920);
        float* akb  = (float*)(ws + 81920 + Z_BYTES);
        float* xb   = (float*)(ws + 81920);             // overlay: z dead after k_ak
        k_z   <<<dim3(36, 16), 256, 0, stream>>>(x, weffp, z);
        k_ak  <<<dim3(36, 16), 256, 0, stream>>>(z, akb);
        k_xbar<<<1152,         256, 0, stream>>>(x, akb, xb);
        k_mat <<<576,          256, 0, stream>>>(xb, wvt, bv, out);
    } else {
        float* part = (float*)(ws + 81920);             // 4.72 MB
        float* akb  = (float*)(ws + 81920 + 4718592);   // 590 KB
        float* xb   = (float*)(ws + 81920);             // overlay: part dead
        k_conv   <<<dim3(16, 3, 8), 192, 0, stream>>>(x, weffp, part);
        k_combine<<<dim3(36, 16),   256, 0, stream>>>(part, akb);
        k_xbar   <<<1152,           256, 0, stream>>>(x, akb, xb);
        k_mat    <<<576,            256, 0, stream>>>(xb, wvt, bv, out);
    }
}

// Round 10
// 84.178 us; speedup vs baseline: 1.1010x; 1.1010x over previous
//
#include <hip/hip_runtime.h>

// ConvAttention collapse:
//   softmax_j(Aq[i]+Ak[j]+ba) == softmax_j(Ak_linear[j])   (i-terms & biases cancel)
//   out[i] = Wv * (sum_j sm[j] * x[j]) + bv                (identical for all i)
// Pipeline: k_prep -> k_z (per-px 25x128 GEMV, c-split 2 for occupancy)
//           -> k_ak (tap shift-sum over partial banks)
//           -> k_xbar (in-thread softmax + weighted avg of x)
//           -> k_mat (128x128 matvec + 16x broadcast store, XCD-swizzled)

#define HW    9216      // 96*96
#define HDIM  96
#define WDIM  96
#define CDIM  128
#define WP    28        // padded taps per row (16B-aligned rows)

__device__ __forceinline__ void fma4(float4& a, const float4& x, const float4& s) {
    a.x += x.x * s.x; a.y += x.y * s.y; a.z += x.z * s.z; a.w += x.w * s.w;
}
__device__ __forceinline__ void axpy4(float4& o, float w, const float4& v) {
    o.x += w * v.x; o.y += w * v.y; o.z += w * v.z; o.w += w * v.w;
}

// ---------------- K0: prep — weffp padded (blocks 0..13) + Wv^T (14..77) --
// weffp[c'][tap] = sum_c Wk[c][c'] * Wa[(128+c)][tap], rows padded to 28.
__global__ void k_prep(const float* __restrict__ Wk, const float* __restrict__ Wa,
                       const float* __restrict__ Wv,
                       float* __restrict__ weffp, float* __restrict__ wvt) {
    const int b = blockIdx.x;
    if (b < 14) {
        int idx = b * 256 + threadIdx.x;
        if (idx < 128 * WP) {
            int cp = idx / WP, tap = idx % WP;
            float s = 0.f;
            if (tap < 25)
                for (int c = 0; c < 128; ++c)
                    s += Wk[c * 128 + cp] * Wa[(128 + c) * 25 + tap];
            weffp[idx] = s;
        }
    } else {
        int idx = (b - 14) * 256 + threadIdx.x;        // 0..16383
        wvt[(idx & 127) * 128 + (idx >> 7)] = Wv[idx]; // wvt[c'][c] = Wv[c][c']
    }
}

// ---------------- K1a: z (single bank, full 128 ch) — round-8 proven form --
__global__ __launch_bounds__(256) void k_z1(const float* __restrict__ x,
                                            const float* __restrict__ weffp,
                                            float* __restrict__ z) {
    __shared__ float wsm[128 * WP];
    const int tid = threadIdx.x;
    for (int i = tid; i < 128 * WP; i += 256) wsm[i] = weffp[i];
    __syncthreads();

    const int j  = blockIdx.y;
    const int hw = blockIdx.x * 256 + tid;
    const float* xb = x + (size_t)j * CDIM * HW + hw;

    float acc[25];
    #pragma unroll
    for (int t = 0; t < 25; ++t) acc[t] = 0.f;

    #pragma unroll 4
    for (int c = 0; c < 128; ++c) {
        float xv = xb[(size_t)c * HW];
        const float* wr = wsm + c * WP;
        #pragma unroll
        for (int t = 0; t < 25; ++t) acc[t] = fmaf(wr[t], xv, acc[t]);
    }
    float* zb = z + (size_t)j * 25 * HW + hw;
    #pragma unroll
    for (int t = 0; t < 25; ++t) zb[(size_t)t * HW] = acc[t];
}

// ---------------- K1b: z c-split 2 — blockIdx.z picks 64-ch half + bank ----
__global__ __launch_bounds__(256) void k_z2(const float* __restrict__ x,
                                            const float* __restrict__ weffp,
                                            float* __restrict__ zp) {
    const int half = blockIdx.z;             // 0 or 1
    const int c0   = half * 64;
    __shared__ float wsm[64 * WP];
    const int tid = threadIdx.x;
    for (int i = tid; i < 64 * WP; i += 256) wsm[i] = weffp[c0 * WP + i];
    __syncthreads();

    const int j  = blockIdx.y;
    const int hw = blockIdx.x * 256 + tid;
    const float* xb = x + (size_t)(j * CDIM + c0) * HW + hw;

    float acc[25];
    #pragma unroll
    for (int t = 0; t < 25; ++t) acc[t] = 0.f;

    #pragma unroll 4
    for (int c = 0; c < 64; ++c) {
        float xv = xb[(size_t)c * HW];
        const float* wr = wsm + c * WP;
        #pragma unroll
        for (int t = 0; t < 25; ++t) acc[t] = fmaf(wr[t], xv, acc[t]);
    }
    float* zb = zp + (size_t)half * 16 * 25 * HW + (size_t)j * 25 * HW + hw;
    #pragma unroll
    for (int t = 0; t < 25; ++t) zb[(size_t)t * HW] = acc[t];
}

// ---------------- K2a: ak from single bank ---------------------------------
__global__ __launch_bounds__(256) void k_ak1(const float* __restrict__ z,
                                             float* __restrict__ ak) {
    const int j  = blockIdx.y;
    const int px = blockIdx.x * 256 + threadIdx.x;
    const int h = px / WDIM, w = px % WDIM;
    const float* zb = z + (size_t)j * 25 * HW + px;
    float s = 0.f;
    #pragma unroll
    for (int kh = 0; kh < 5; ++kh) {
        const bool rok = (unsigned)(h + kh - 2) < (unsigned)HDIM;
        #pragma unroll
        for (int kw = 0; kw < 5; ++kw) {
            const bool ok = rok && ((unsigned)(w + kw - 2) < (unsigned)WDIM);
            const int t = kh * 5 + kw;
            s += ok ? zb[t * HW + (kh - 2) * WDIM + (kw - 2)] : 0.f;
        }
    }
    ak[(size_t)j * HW + px] = s;
}

// ---------------- K2b: ak from two partial banks ---------------------------
__global__ __launch_bounds__(256) void k_ak2(const float* __restrict__ z,
                                             float* __restrict__ ak) {
    const size_t BANK = (size_t)16 * 25 * HW;
    const int j  = blockIdx.y;
    const int px = blockIdx.x * 256 + threadIdx.x;
    const int h = px / WDIM, w = px % WDIM;
    const float* zb = z + (size_t)j * 25 * HW + px;
    float s = 0.f;
    #pragma unroll
    for (int kh = 0; kh < 5; ++kh) {
        const bool rok = (unsigned)(h + kh - 2) < (unsigned)HDIM;
        #pragma unroll
        for (int kw = 0; kw < 5; ++kw) {
            const bool ok = rok && ((unsigned)(w + kw - 2) < (unsigned)WDIM);
            const int t = kh * 5 + kw;
            const int idx = t * HW + (kh - 2) * WDIM + (kw - 2);
            s += ok ? (zb[idx] + zb[BANK + idx]) : 0.f;
        }
    }
    ak[(size_t)j * HW + px] = s;
}

// ---------------- fallback conv path (small-ws; proven round 5) ------------
__global__ __launch_bounds__(192) void k_conv(const float* __restrict__ x,
                                              const float* __restrict__ weffp,
                                              float* __restrict__ part) {
    const int j  = blockIdx.x;
    const int rt = blockIdx.y;
    const int g  = blockIdx.z;
    const int c0 = g * 16;
    __shared__ float tile[36 * 104];
    __shared__ float wsm[16 * WP];
    const int tid = threadIdx.x;
    for (int i = tid; i < 16 * WP; i += 192) wsm[i] = weffp[c0 * WP + i];
    const int cq = tid % 24;
    const int rg = tid / 24;
    const int r0 = rg * 4;
    const int rowbase = rt * 32;

    float4 acc[4];
    acc[0] = acc[1] = acc[2] = acc[3] = make_float4(0.f, 0.f, 0.f, 0.f);

    for (int ch = 0; ch < 16; ++ch) {
        const float* xc = x + (size_t)(j * CDIM + c0 + ch) * HW;
        __syncthreads();
        for (int idx = tid; idx < 36 * 26; idx += 192) {
            int r = idx / 26, q = idx % 26;
            int gr = rowbase - 2 + r;
            int gc = q * 4 - 4;
            float4 v = make_float4(0.f, 0.f, 0.f, 0.f);
            if (gr >= 0 && gr < HDIM && gc >= 0 && gc < WDIM)
                v = *(const float4*)(xc + gr * WDIM + gc);
            *(float4*)(tile + r * 104 + q * 4) = v;
        }
        __syncthreads();
        const float* wc = wsm + ch * WP;
        for (int rr = 0; rr < 8; ++rr) {
            const float* trow = tile + (r0 + rr) * 104 + cq * 4;
            float4 a  = *(const float4*)(trow);
            float4 b  = *(const float4*)(trow + 4);
            float4 c4 = *(const float4*)(trow + 8);
            float win[12] = {a.x, a.y, a.z, a.w, b.x, b.y, b.z, b.w,
                             c4.x, c4.y, c4.z, c4.w};
            #pragma unroll
            for (int orow = 0; orow < 4; ++orow) {
                int kh = rr - orow;
                if (kh < 0 || kh > 4) continue;
                #pragma unroll
                for (int kw = 0; kw < 5; ++kw) {
                    float w = wc[kh * 5 + kw];
                    acc[orow].x += w * win[kw + 2];
                    acc[orow].y += w * win[kw + 3];
                    acc[orow].z += w * win[kw + 4];
                    acc[orow].w += w * win[kw + 5];
                }
            }
        }
    }
    float* pr = part + (size_t)(g * 16 + j) * HW;
    #pragma unroll
    for (int orow = 0; orow < 4; ++orow) {
        int row = rowbase + r0 + orow;
        *(float4*)(pr + row * WDIM + cq * 4) = acc[orow];
    }
}

__global__ void k_combine(const float* __restrict__ part, float* __restrict__ ak) {
    const int j  = blockIdx.y;
    const int px = blockIdx.x * 256 + threadIdx.x;
    float s = 0.f;
    #pragma unroll
    for (int g = 0; g < 8; ++g) s += part[(size_t)(g * 16 + j) * HW + px];
    ak[(size_t)j * HW + px] = s;
}

// ---------------- K3: xbar[cp][px] = sum_j softmax_j(ak)[px] * x[j][cp][px] -
__global__ __launch_bounds__(256) void k_xbar(const float* __restrict__ x,
                                              const float* __restrict__ ak,
                                              float* __restrict__ xbar) {
    const int b  = blockIdx.x;
    const int cp = b / 9;
    const int px = (b % 9) * 1024 + threadIdx.x * 4;

    float4 av[16];
    #pragma unroll
    for (int j = 0; j < 16; ++j)
        av[j] = *(const float4*)(ak + (size_t)j * HW + px);

    float4 m = av[0];
    #pragma unroll
    for (int j = 1; j < 16; ++j) {
        m.x = fmaxf(m.x, av[j].x); m.y = fmaxf(m.y, av[j].y);
        m.z = fmaxf(m.z, av[j].z); m.w = fmaxf(m.w, av[j].w);
    }
    float4 tot = make_float4(0.f, 0.f, 0.f, 0.f);
    #pragma unroll
    for (int j = 0; j < 16; ++j) {
        av[j].x = __expf(av[j].x - m.x); av[j].y = __expf(av[j].y - m.y);
        av[j].z = __expf(av[j].z - m.z); av[j].w = __expf(av[j].w - m.w);
        tot.x += av[j].x; tot.y += av[j].y; tot.z += av[j].z; tot.w += av[j].w;
    }
    float4 inv = make_float4(1.f / tot.x, 1.f / tot.y, 1.f / tot.z, 1.f / tot.w);

    float4 acc = make_float4(0.f, 0.f, 0.f, 0.f);
    #pragma unroll
    for (int j = 0; j < 16; ++j) {
        float4 xv = *(const float4*)(x + (size_t)(j * CDIM + cp) * HW + px);
        fma4(acc, xv, av[j]);
    }
    acc.x *= inv.x; acc.y *= inv.y; acc.z *= inv.z; acc.w *= inv.w;
    *(float4*)(xbar + (size_t)cp * HW + px) = acc;
}

// ---------------- K4: out[i][c][px] = Wv*xbar + bv, 16x broadcast ----------
__global__ __launch_bounds__(256) void k_mat(const float* __restrict__ xbar,
                                             const float* __restrict__ wvt,
                                             const float* __restrict__ bv,
                                             float* __restrict__ out) {
    __shared__ float lx[128 * 16];
    const int b    = blockIdx.x;
    const int tile = (b & 7) * 72 + (b >> 3);   // 576 = 8 * 72
    const int px0  = tile * 16;
    const int tid  = threadIdx.x;

    #pragma unroll
    for (int i = 0; i < 2; ++i) {
        int lin = tid + i * 256;                // 0..511
        int cp = lin >> 2, q = lin & 3;
        *(float4*)(lx + cp * 16 + q * 4) =
            *(const float4*)(xbar + (size_t)cp * HW + px0 + q * 4);
    }
    __syncthreads();

    const int q  = tid & 3;
    const int c0 = (tid >> 2) * 2;
    float4 o0 = make_float4(0.f, 0.f, 0.f, 0.f), o1 = o0;
    #pragma unroll 4
    for (int cp = 0; cp < 128; ++cp) {
        float4 xv = *(const float4*)(lx + cp * 16 + q * 4);
        float2 wv = *(const float2*)(wvt + cp * 128 + c0);
        axpy4(o0, wv.x, xv);
        axpy4(o1, wv.y, xv);
    }
    float b0 = bv[c0], b1 = bv[c0 + 1];
    o0.x += b0; o0.y += b0; o0.z += b0; o0.w += b0;
    o1.x += b1; o1.y += b1; o1.z += b1; o1.w += b1;

    for (int i = 0; i < 16; ++i) {
        float* ob = out + (size_t)(i * CDIM + c0) * HW + px0 + q * 4;
        *(float4*)(ob)      = o0;
        *(float4*)(ob + HW) = o1;
    }
}

extern "C" void kernel_launch(void* const* d_in, const int* in_sizes, int n_in,
                              void* d_out, int out_size, void* d_ws, size_t ws_size,
                              hipStream_t stream) {
    const float* x  = (const float*)d_in[0];
    const float* Wk = (const float*)d_in[3];
    const float* Wv = (const float*)d_in[5];
    const float* bv = (const float*)d_in[6];
    const float* Wa = (const float*)d_in[7];
    float* out = (float*)d_out;

    char* ws = (char*)d_ws;
    float* weffp = (float*)(ws);            // 128*28*4 = 14,336 B
    float* wvt   = (float*)(ws + 16384);    // 64 KB, ends 81920

    k_prep<<<78, 256, 0, stream>>>(Wk, Wa, Wv, weffp, wvt);

    const size_t Z_BYTES   = (size_t)16 * 25 * HW * 4;        // 14.75 MB
    const size_t AK_BYTES  = (size_t)16 * HW * 4;             // 590 KB
    const size_t NEED_BIG1 = 81920 + Z_BYTES + AK_BYTES;      // 15.4 MB (proven)
    const size_t NEED_BIG2 = 81920 + 2 * Z_BYTES + AK_BYTES;  // 30.2 MB

    if (ws_size >= NEED_BIG2) {
        float* z   = (float*)(ws + 81920);                  // 2 banks
        float* akb = (float*)(ws + 81920 + 2 * Z_BYTES);
        float* xb  = (float*)(ws + 81920);                  // overlay: z dead after k_ak2
        k_z2  <<<dim3(36, 16, 2), 256, 0, stream>>>(x, weffp, z);
        k_ak2 <<<dim3(36, 16),    256, 0, stream>>>(z, akb);
        k_xbar<<<1152,            256, 0, stream>>>(x, akb, xb);
        k_mat <<<576,             256, 0, stream>>>(xb, wvt, bv, out);
    } else if (ws_size >= NEED_BIG1) {
        float* z   = (float*)(ws + 81920);
        float* akb = (float*)(ws + 81920 + Z_BYTES);
        float* xb  = (float*)(ws + 81920);                  // overlay: z dead after k_ak1
        k_z1  <<<dim3(36, 16), 256, 0, stream>>>(x, weffp, z);
        k_ak1 <<<dim3(36, 16), 256, 0, stream>>>(z, akb);
        k_xbar<<<1152,         256, 0, stream>>>(x, akb, xb);
        k_mat <<<576,          256, 0, stream>>>(xb, wvt, bv, out);
    } else {
        float* part = (float*)(ws + 81920);                 // 4.72 MB
        float* akb  = (float*)(ws + 81920 + 4718592);       // 590 KB
        float* xb   = (float*)(ws + 81920);                 // overlay: part dead
        k_conv   <<<dim3(16, 3, 8), 192, 0, stream>>>(x, weffp, part);
        k_combine<<<dim3(36, 16),   256, 0, stream>>>(part, akb);
        k_xbar   <<<1152,           256, 0, stream>>>(x, akb, xb);
        k_mat    <<<576,            256, 0, stream>>>(xb, wvt, bv, out);
    }
}